// Round 5
// baseline (3383.617 us; speedup 1.0000x reference)
//
#include <hip/hip_runtime.h>
#include <cstdint>

#define LN_EPS 1e-5f
#define BMS 64
#define BNS 64
#define BKS 16

// ---------------------------------------------------------------------------
// prep: Wm[k,f] = W_l[k,f] * adj[k,f]  (fp32 elementwise, float4)
// ---------------------------------------------------------------------------
__global__ __launch_bounds__(256) void prep_w(
    const float* __restrict__ W, const float* __restrict__ adj,
    float* __restrict__ Wm, size_t n4)
{
    size_t i = (size_t)blockIdx.x * 256 + threadIdx.x;
    if (i < n4) {
        float4 w = ((const float4*)W)[i];
        float4 a = ((const float4*)adj)[i];
        float4 o;
        o.x = w.x * a.x; o.y = w.y * a.y; o.z = w.z * a.z; o.w = w.w * a.w;
        ((float4*)Wm)[i] = o;
    }
}

// ---------------------------------------------------------------------------
// C[p,f] = relu( sum_k A[p,k]*Wm[k,f] + bias[f] ) + A[p,f]     (all fp32)
// Classic tiled SGEMM: 64x64 tile, BK=16, 256 threads, 4x4 micro-tile.
// Requires F == K (residual read from A). Correctness-first anchor kernel.
// ---------------------------------------------------------------------------
__global__ __launch_bounds__(256) void gemm_simple(
    const float* __restrict__ A,    // P x F (h_in)
    const float* __restrict__ Wm,   // F x F
    const float* __restrict__ bias, // F
    float* __restrict__ C,          // P x F
    int P, int F)
{
    __shared__ float As[BKS][BMS + 1];
    __shared__ float Bs[BKS][BNS + 1];

    const int t  = threadIdx.x;
    const int tx = t & 15;          // 0..15 -> output cols
    const int ty = t >> 4;          // 0..15 -> output rows
    const int rowBlk = blockIdx.y * BMS;
    const int colBlk = blockIdx.x * BNS;

    float acc[4][4] = {};

    for (int k0 = 0; k0 < F; k0 += BKS) {
        // stage A: 64 rows x 16 k  (float4 per thread, k-contiguous)
        {
            const int m  = t >> 2;            // 0..63
            const int kq = (t & 3) * 4;       // 0,4,8,12
            float4 v = *(const float4*)(A + (size_t)(rowBlk + m) * F + k0 + kq);
            As[kq + 0][m] = v.x; As[kq + 1][m] = v.y;
            As[kq + 2][m] = v.z; As[kq + 3][m] = v.w;
        }
        // stage B: 16 k x 64 f  (float4 per thread, f-contiguous)
        {
            const int k  = t >> 4;            // 0..15
            const int f4 = (t & 15) * 4;      // 0..60
            float4 v = *(const float4*)(Wm + (size_t)(k0 + k) * F + colBlk + f4);
            Bs[k][f4 + 0] = v.x; Bs[k][f4 + 1] = v.y;
            Bs[k][f4 + 2] = v.z; Bs[k][f4 + 3] = v.w;
        }
        __syncthreads();

#pragma unroll
        for (int kk = 0; kk < BKS; ++kk) {
            float a[4], b[4];
#pragma unroll
            for (int i = 0; i < 4; ++i) a[i] = As[kk][ty * 4 + i];
#pragma unroll
            for (int j = 0; j < 4; ++j) b[j] = Bs[kk][tx * 4 + j];
#pragma unroll
            for (int i = 0; i < 4; ++i)
#pragma unroll
                for (int j = 0; j < 4; ++j)
                    acc[i][j] = fmaf(a[i], b[j], acc[i][j]);
        }
        __syncthreads();
    }

    // epilogue: bias + relu + residual (fp32 out)
#pragma unroll
    for (int i = 0; i < 4; ++i) {
        const int row = rowBlk + ty * 4 + i;
#pragma unroll
        for (int j = 0; j < 4; ++j) {
            const int col = colBlk + tx * 4 + j;
            float y = fmaxf(acc[i][j] + bias[col], 0.f)
                      + A[(size_t)row * F + col];
            C[(size_t)row * F + col] = y;
        }
    }
}

// ---------------------------------------------------------------------------
// LayerNorm over F=1024 (fp32 in/out), one block per row, float4 per thread.
// ---------------------------------------------------------------------------
__global__ __launch_bounds__(256) void ln_f32(
    const float* __restrict__ Y, float* __restrict__ O, int F)
{
    const int row = blockIdx.x;
    const int tid = threadIdx.x;
    const int wave = tid >> 6, lane = tid & 63;
    const float* y = Y + (size_t)row * F;

    float4 v = ((const float4*)y)[tid];
    float s  = v.x + v.y + v.z + v.w;
    float s2 = v.x * v.x + v.y * v.y + v.z * v.z + v.w * v.w;
#pragma unroll
    for (int off = 32; off > 0; off >>= 1) {
        s  += __shfl_down(s,  off, 64);
        s2 += __shfl_down(s2, off, 64);
    }
    __shared__ float ws[8];
    if (lane == 0) { ws[wave] = s; ws[4 + wave] = s2; }
    __syncthreads();
    float ts  = ws[0] + ws[1] + ws[2] + ws[3];
    float ts2 = ws[4] + ws[5] + ws[6] + ws[7];
    float mean = ts / (float)F;
    float var  = ts2 / (float)F - mean * mean;
    float rstd = rsqrtf(var + LN_EPS);

    float4 o;
    o.x = (v.x - mean) * rstd;
    o.y = (v.y - mean) * rstd;
    o.z = (v.z - mean) * rstd;
    o.w = (v.w - mean) * rstd;
    ((float4*)(O + (size_t)row * F))[tid] = o;
}

// ---------------------------------------------------------------------------
extern "C" void kernel_launch(void* const* d_in, const int* in_sizes, int n_in,
                              void* d_out, int out_size, void* d_ws, size_t ws_size,
                              hipStream_t stream) {
    const float* x    = (const float*)d_in[0];   // fp32
    const float* adj  = (const float*)d_in[1];   // fp32
    const float* W    = (const float*)d_in[2];   // fp32 (L,F,F)
    const float* bias = (const float*)d_in[3];   // fp32 (L,F)
    float* out = (float*)d_out;                  // fp32 (N,F)

    const int L = in_sizes[2] / in_sizes[1];     // 5
    const int F = in_sizes[3] / L;               // 1024
    const int N = in_sizes[0] / F;               // 16384

    const size_t ff = (size_t)F * F;

    // ws layout: Wm (ff fp32) + tmp (panel*F fp32). Rows propagate
    // independently, so h lives in d_out and we process row panels:
    //   gemm(h rows P -> tmp), ln(tmp -> h rows P).
    float* Wm  = (float*)d_ws;
    float* tmp = Wm + ff;

    int panel = N;
    while (panel > BMS &&
           ws_size < ff * sizeof(float) + (size_t)panel * F * sizeof(float))
        panel >>= 1;

    for (int l = 0; l < L; ++l) {
        prep_w<<<(unsigned)((ff / 4 + 255) / 256), 256, 0, stream>>>(
            W + (size_t)l * ff, adj, Wm, ff / 4);
        // layer 0 reads x directly (never written); later layers read d_out
        const float* hbase = (l == 0) ? x : out;
        for (int p0 = 0; p0 < N; p0 += panel) {
            gemm_simple<<<dim3(F / BNS, panel / BMS), 256, 0, stream>>>(
                hbase + (size_t)p0 * F, Wm, bias + (size_t)l * F, tmp,
                panel, F);
            ln_f32<<<panel, 256, 0, stream>>>(tmp, out + (size_t)p0 * F, F);
        }
    }
}

// Round 6
// 770.877 us; speedup vs baseline: 4.3893x; 4.3893x over previous
//
#include <hip/hip_runtime.h>
#include <cstdint>

typedef unsigned short u16;
typedef __bf16 bf16x8 __attribute__((ext_vector_type(8)));
typedef float f32x4 __attribute__((ext_vector_type(4)));

#define BM 128
#define BN 128
#define BK 32
#define LN_EPS 1e-5f

__device__ __forceinline__ u16 f2b(float f) {
    union { float f; unsigned int i; } v;
    v.f = f;
    unsigned int u = v.i;
    unsigned int r = (u + 0x7FFFu + ((u >> 16) & 1u)) >> 16;  // RNE
    return (u16)r;
}

// ---------------------------------------------------------------------------
// init: h_f32 = x (copy), h_bf16 = bf16(x). float4 in, float4 + ushort4 out.
// ---------------------------------------------------------------------------
__global__ __launch_bounds__(256) void init_h(
    const float* __restrict__ X, float* __restrict__ Hf,
    u16* __restrict__ Hb, size_t n4)
{
    size_t i = (size_t)blockIdx.x * 256 + threadIdx.x;
    if (i < n4) {
        float4 v = ((const float4*)X)[i];
        ((float4*)Hf)[i] = v;
        ushort4 o;
        o.x = f2b(v.x); o.y = f2b(v.y); o.z = f2b(v.z); o.w = f2b(v.w);
        ((ushort4*)Hb)[i] = o;
    }
}

// ---------------------------------------------------------------------------
// Prep: WT[f][k] = bf16( W[k][f] * adj[k][f] ), fp32 inputs, one layer.
// grid (F/64, F/64), block 256. LDS transpose for coalescing both ways.
// ---------------------------------------------------------------------------
__global__ __launch_bounds__(256) void prep_weights(
    const float* __restrict__ W, const float* __restrict__ adj,
    u16* __restrict__ WT, int F)
{
    __shared__ float tile[64][65];
    const int tid = threadIdx.x;
    const int kb = blockIdx.y * 64;
    const int fb = blockIdx.x * 64;
    const int c  = tid & 63;
    const int r0 = tid >> 6;

#pragma unroll
    for (int i = 0; i < 16; ++i) {
        int kl = r0 + i * 4;
        int k = kb + kl, f = fb + c;
        tile[kl][c] = W[(size_t)k * F + f] * adj[(size_t)k * F + f];
    }
    __syncthreads();
#pragma unroll
    for (int i = 0; i < 16; ++i) {
        int fl = r0 + i * 4;
        int f = fb + fl, k = kb + c;
        WT[(size_t)f * F + k] = f2b(tile[c][fl]);
    }
}

// ---------------------------------------------------------------------------
// GEMM: Cf[n,f] = relu( sum_k Ab[n,k]*BT[f,k] + bias[f] ) + Cf[n,f]
// Ab, BT bf16; bias, Cf fp32 (in-place residual+store — safe: each element
// is read and written only by its owning thread). m93 structure: 128x128
// tile, BK=32, uint4 load + LDS store, 16x16x32 MFMA, 4 waves. K == F.
// ---------------------------------------------------------------------------
__global__ __launch_bounds__(256) void gemm_bf16(
    const u16* __restrict__ Ab,    // N x K  (h mirror, bf16)
    const u16* __restrict__ BT,    // F x K  (WeffT, bf16)
    const float* __restrict__ bias,// F (fp32)
    float* __restrict__ Cf,        // N x F (fp32, in/out)
    int N, int K, int F)
{
    __shared__ __align__(16) u16 lds_a[BM * BK];
    __shared__ __align__(16) u16 lds_b[BN * BK];

    const int tid  = threadIdx.x;
    const int wave = tid >> 6;
    const int lane = tid & 63;
    const int wm = wave >> 1;
    const int wn = wave & 1;
    const int q  = lane >> 4;
    const int r16 = lane & 15;

    const int rowBlk = blockIdx.y * BM;
    const int colBlk = blockIdx.x * BN;

    f32x4 acc[4][4];
    const f32x4 zero = {0.f, 0.f, 0.f, 0.f};
#pragma unroll
    for (int i = 0; i < 4; ++i)
#pragma unroll
        for (int j = 0; j < 4; ++j) acc[i][j] = zero;

    uint4* sa = (uint4*)lds_a;    // 512 x 16B = 128 rows x 32 k
    uint4* sb = (uint4*)lds_b;

    for (int k0 = 0; k0 < K; k0 += BK) {
#pragma unroll
        for (int c = 0; c < 2; ++c) {
            int chunk = tid + c * 256;
            int row = chunk >> 2;
            int cq  = chunk & 3;
            sa[chunk] = *(const uint4*)(Ab + (size_t)(rowBlk + row) * K + k0 + cq * 8);
            sb[chunk] = *(const uint4*)(BT + (size_t)(colBlk + row) * K + k0 + cq * 8);
        }
        __syncthreads();

        const bf16x8* pa = (const bf16x8*)lds_a;
        const bf16x8* pb = (const bf16x8*)lds_b;
        bf16x8 af[4], bfr[4];
#pragma unroll
        for (int mi = 0; mi < 4; ++mi)
            af[mi] = pa[(wm * 64 + mi * 16 + r16) * 4 + q];
#pragma unroll
        for (int ni = 0; ni < 4; ++ni)
            bfr[ni] = pb[(wn * 64 + ni * 16 + r16) * 4 + q];
#pragma unroll
        for (int mi = 0; mi < 4; ++mi)
#pragma unroll
            for (int ni = 0; ni < 4; ++ni)
                acc[mi][ni] = __builtin_amdgcn_mfma_f32_16x16x32_bf16(
                    af[mi], bfr[ni], acc[mi][ni], 0, 0, 0);
        __syncthreads();
    }

    // epilogue: C/D layout col=lane&15, row=quad*4+reg  [m89/m91]
#pragma unroll
    for (int ni = 0; ni < 4; ++ni) {
        const int gcol = colBlk + wn * 64 + ni * 16 + r16;
        const float bv = bias[gcol];
#pragma unroll
        for (int mi = 0; mi < 4; ++mi) {
            const int rbase = rowBlk + wm * 64 + mi * 16 + q * 4;
#pragma unroll
            for (int j = 0; j < 4; ++j) {
                const int grow = rbase + j;
                float* p = Cf + (size_t)grow * F + gcol;
                float y = fmaxf(acc[mi][ni][j] + bv, 0.f) + *p;  // fp32 residual
                *p = y;
            }
        }
    }
}

// ---------------------------------------------------------------------------
// LayerNorm over F=1024 fp32 in-place + refresh bf16 mirror.
// One block per row, float4 per thread.
// ---------------------------------------------------------------------------
__global__ __launch_bounds__(256) void ln_fused(
    float* __restrict__ H, u16* __restrict__ Hb, int F)
{
    const int row = blockIdx.x;
    const int tid = threadIdx.x;
    const int wave = tid >> 6, lane = tid & 63;
    float* y = H + (size_t)row * F;

    float4 v = ((const float4*)y)[tid];
    float s  = v.x + v.y + v.z + v.w;
    float s2 = v.x * v.x + v.y * v.y + v.z * v.z + v.w * v.w;
#pragma unroll
    for (int off = 32; off > 0; off >>= 1) {
        s  += __shfl_down(s,  off, 64);
        s2 += __shfl_down(s2, off, 64);
    }
    __shared__ float ws[8];
    if (lane == 0) { ws[wave] = s; ws[4 + wave] = s2; }
    __syncthreads();
    float ts  = ws[0] + ws[1] + ws[2] + ws[3];
    float ts2 = ws[4] + ws[5] + ws[6] + ws[7];
    float mean = ts / (float)F;
    float var  = ts2 / (float)F - mean * mean;
    float rstd = rsqrtf(var + LN_EPS);

    float4 o;
    o.x = (v.x - mean) * rstd;
    o.y = (v.y - mean) * rstd;
    o.z = (v.z - mean) * rstd;
    o.w = (v.w - mean) * rstd;
    ((float4*)y)[tid] = o;

    ushort4 ob;
    ob.x = f2b(o.x); ob.y = f2b(o.y); ob.z = f2b(o.z); ob.w = f2b(o.w);
    ((ushort4*)(Hb + (size_t)row * F))[tid] = ob;
}

// ---------------------------------------------------------------------------
extern "C" void kernel_launch(void* const* d_in, const int* in_sizes, int n_in,
                              void* d_out, int out_size, void* d_ws, size_t ws_size,
                              hipStream_t stream) {
    const float* x    = (const float*)d_in[0];   // fp32 (N,F)
    const float* adj  = (const float*)d_in[1];   // fp32 (F,F)
    const float* W    = (const float*)d_in[2];   // fp32 (L,F,F)
    const float* bias = (const float*)d_in[3];   // fp32 (L,F)
    float* out = (float*)d_out;                  // fp32 (N,F)

    const int L = in_sizes[2] / in_sizes[1];     // 5
    const int F = in_sizes[3] / L;               // 1024
    const int N = in_sizes[0] / F;               // 16384

    const size_t nf = (size_t)N * F;
    const size_t ff = (size_t)F * F;

    // ws: WT (ff bf16, 2.1 MB, reused per layer) + h_bf16 mirror (nf bf16,
    // 33.6 MB). Total 35.7 MB — well under the >=71 MB proven in R5.
    u16* WT = (u16*)d_ws;
    u16* Hb = WT + ff;

    init_h<<<(unsigned)((nf / 4 + 255) / 256), 256, 0, stream>>>(x, out, Hb, nf / 4);

    for (int l = 0; l < L; ++l) {
        prep_weights<<<dim3(F / 64, F / 64), 256, 0, stream>>>(
            W + (size_t)l * ff, adj, WT, F);
        gemm_bf16<<<dim3(F / BN, N / BM), 256, 0, stream>>>(
            Hb, WT, bias + (size_t)l * F, out, N, F, F);
        ln_fused<<<N, 256, 0, stream>>>(out, Hb, F);
    }
}

// Round 7
// 689.082 us; speedup vs baseline: 4.9103x; 1.1187x over previous
//
#include <hip/hip_runtime.h>
#include <cstdint>

typedef unsigned short u16;
typedef __bf16 bf16x8 __attribute__((ext_vector_type(8)));
typedef float f32x4 __attribute__((ext_vector_type(4)));

#define BM 128
#define BN 128
#define BK 32
#define LN_EPS 1e-5f

__device__ __forceinline__ u16 f2b(float f) {
    union { float f; unsigned int i; } v;
    v.f = f;
    unsigned int u = v.i;
    unsigned int r = (u + 0x7FFFu + ((u >> 16) & 1u)) >> 16;  // RNE
    return (u16)r;
}

__device__ __forceinline__ void async_copy16(const u16* g, u16* l) {
    __builtin_amdgcn_global_load_lds(
        (const __attribute__((address_space(1))) u16*)g,
        (__attribute__((address_space(3))) u16*)l,
        16, 0, 0);
}

// ---------------------------------------------------------------------------
// init: h_f32 = x (copy), h_bf16 = bf16(x).
// ---------------------------------------------------------------------------
__global__ __launch_bounds__(256) void init_h(
    const float* __restrict__ X, float* __restrict__ Hf,
    u16* __restrict__ Hb, size_t n4)
{
    size_t i = (size_t)blockIdx.x * 256 + threadIdx.x;
    if (i < n4) {
        float4 v = ((const float4*)X)[i];
        ((float4*)Hf)[i] = v;
        ushort4 o;
        o.x = f2b(v.x); o.y = f2b(v.y); o.z = f2b(v.z); o.w = f2b(v.w);
        ((ushort4*)Hb)[i] = o;
    }
}

// ---------------------------------------------------------------------------
// Prep all layers: WT[z][f][k] = bf16( W[z][k][f] * adj[k][f] ), fp32 in.
// grid (F/64, F/64, L), block 256. LDS transpose for coalescing both ways.
// ---------------------------------------------------------------------------
__global__ __launch_bounds__(256) void prep_weights(
    const float* __restrict__ W, const float* __restrict__ adj,
    u16* __restrict__ WT, int F)
{
    __shared__ float tile[64][65];
    const int tid = threadIdx.x;
    const size_t lofs = (size_t)blockIdx.z * F * F;
    const int kb = blockIdx.y * 64;
    const int fb = blockIdx.x * 64;
    const int c  = tid & 63;
    const int r0 = tid >> 6;

#pragma unroll
    for (int i = 0; i < 16; ++i) {
        int kl = r0 + i * 4;
        int k = kb + kl, f = fb + c;
        tile[kl][c] = W[lofs + (size_t)k * F + f] * adj[(size_t)k * F + f];
    }
    __syncthreads();
#pragma unroll
    for (int i = 0; i < 16; ++i) {
        int fl = r0 + i * 4;
        int f = fb + fl, k = kb + c;
        WT[lofs + (size_t)f * F + k] = f2b(tile[c][fl]);
    }
}

// ---------------------------------------------------------------------------
// GEMM: Cf[n,f] = relu( sum_k Ab[n,k]*BT[f,k] + bias[f] ) + Cf[n,f]
// m97 structure: 128x128 tile, BK=32, global_load_lds dwordx4 staging,
// 16x16x32 MFMA, 4 waves. 1-D grid with XCD-aware swizzle: b&7 selects the
// XCD-group; each group owns nRow/8 row-panels x all col-tiles (row-major)
// so the concurrent working set (~2MB A + 2MB B) fits one XCD's 4MB L2.
// ---------------------------------------------------------------------------
__global__ __launch_bounds__(256) void gemm_bf16(
    const u16* __restrict__ Ab,    // N x K  (h mirror, bf16)
    const u16* __restrict__ BT,    // F x K  (WeffT, bf16)
    const float* __restrict__ bias,// F (fp32)
    float* __restrict__ Cf,        // N x F (fp32, in/out)
    int N, int K, int F)
{
    __shared__ __align__(16) u16 lds_a[BM * BK];
    __shared__ __align__(16) u16 lds_b[BN * BK];

    const int tid  = threadIdx.x;
    const int wave = tid >> 6;
    const int lane = tid & 63;
    const int wm = wave >> 1;
    const int wn = wave & 1;
    const int q  = lane >> 4;
    const int r16 = lane & 15;

    // XCD swizzle
    const int nRow = N / BM, nCol = F / BN;
    int rowTile, colTile;
    if ((nRow & 7) == 0) {
        const int b = blockIdx.x;
        const int x = b & 7;            // XCD group
        const int k = b >> 3;           // 0..nRow/8*nCol-1
        rowTile = x * (nRow >> 3) + k / nCol;
        colTile = k % nCol;
    } else {
        rowTile = blockIdx.x / nCol;
        colTile = blockIdx.x % nCol;
    }
    const int rowBlk = rowTile * BM;
    const int colBlk = colTile * BN;

    f32x4 acc[4][4];
    const f32x4 zero = {0.f, 0.f, 0.f, 0.f};
#pragma unroll
    for (int i = 0; i < 4; ++i)
#pragma unroll
        for (int j = 0; j < 4; ++j) acc[i][j] = zero;

    // staging geometry: per wave-issue, 64 lanes x 16B cover 16 rows x 32 k.
    // LDS offset = chunk*1024 + lane*16  (wave-uniform base + lane*size).
    const int ldRow = lane >> 2;        // 0..15
    const int ldCol = (lane & 3) * 8;   // 0,8,16,24 elements

    for (int k0 = 0; k0 < K; k0 += BK) {
#pragma unroll
        for (int c = 0; c < 2; ++c) {
            int chunk = wave * 2 + c;          // 0..7
            int row = chunk * 16 + ldRow;      // 0..127
            const u16* ga = Ab + (size_t)(rowBlk + row) * K + k0 + ldCol;
            const u16* gb = BT + (size_t)(colBlk + row) * K + k0 + ldCol;
            async_copy16(ga, &lds_a[chunk * 16 * BK]);
            async_copy16(gb, &lds_b[chunk * 16 * BK]);
        }
        __syncthreads();

        const bf16x8* pa = (const bf16x8*)lds_a;
        const bf16x8* pb = (const bf16x8*)lds_b;
        bf16x8 af[4], bfr[4];
#pragma unroll
        for (int mi = 0; mi < 4; ++mi)
            af[mi] = pa[(wm * 64 + mi * 16 + r16) * 4 + q];
#pragma unroll
        for (int ni = 0; ni < 4; ++ni)
            bfr[ni] = pb[(wn * 64 + ni * 16 + r16) * 4 + q];
#pragma unroll
        for (int mi = 0; mi < 4; ++mi)
#pragma unroll
            for (int ni = 0; ni < 4; ++ni)
                acc[mi][ni] = __builtin_amdgcn_mfma_f32_16x16x32_bf16(
                    af[mi], bfr[ni], acc[mi][ni], 0, 0, 0);
        __syncthreads();
    }

    // epilogue: C/D layout col=lane&15, row=quad*4+reg  [m89/m91]
#pragma unroll
    for (int ni = 0; ni < 4; ++ni) {
        const int gcol = colBlk + wn * 64 + ni * 16 + r16;
        const float bv = bias[gcol];
#pragma unroll
        for (int mi = 0; mi < 4; ++mi) {
            const int rbase = rowBlk + wm * 64 + mi * 16 + q * 4;
#pragma unroll
            for (int j = 0; j < 4; ++j) {
                const int grow = rbase + j;
                float* p = Cf + (size_t)grow * F + gcol;
                float y = fmaxf(acc[mi][ni][j] + bv, 0.f) + *p;  // fp32 residual
                *p = y;
            }
        }
    }
}

// ---------------------------------------------------------------------------
// LayerNorm over F=1024 fp32 in-place + refresh bf16 mirror.
// ---------------------------------------------------------------------------
__global__ __launch_bounds__(256) void ln_fused(
    float* __restrict__ H, u16* __restrict__ Hb, int F)
{
    const int row = blockIdx.x;
    const int tid = threadIdx.x;
    const int wave = tid >> 6, lane = tid & 63;
    float* y = H + (size_t)row * F;

    float4 v = ((const float4*)y)[tid];
    float s  = v.x + v.y + v.z + v.w;
    float s2 = v.x * v.x + v.y * v.y + v.z * v.z + v.w * v.w;
#pragma unroll
    for (int off = 32; off > 0; off >>= 1) {
        s  += __shfl_down(s,  off, 64);
        s2 += __shfl_down(s2, off, 64);
    }
    __shared__ float ws[8];
    if (lane == 0) { ws[wave] = s; ws[4 + wave] = s2; }
    __syncthreads();
    float ts  = ws[0] + ws[1] + ws[2] + ws[3];
    float ts2 = ws[4] + ws[5] + ws[6] + ws[7];
    float mean = ts / (float)F;
    float var  = ts2 / (float)F - mean * mean;
    float rstd = rsqrtf(var + LN_EPS);

    float4 o;
    o.x = (v.x - mean) * rstd;
    o.y = (v.y - mean) * rstd;
    o.z = (v.z - mean) * rstd;
    o.w = (v.w - mean) * rstd;
    ((float4*)y)[tid] = o;

    ushort4 ob;
    ob.x = f2b(o.x); ob.y = f2b(o.y); ob.z = f2b(o.z); ob.w = f2b(o.w);
    ((ushort4*)(Hb + (size_t)row * F))[tid] = ob;
}

// ---------------------------------------------------------------------------
extern "C" void kernel_launch(void* const* d_in, const int* in_sizes, int n_in,
                              void* d_out, int out_size, void* d_ws, size_t ws_size,
                              hipStream_t stream) {
    const float* x    = (const float*)d_in[0];   // fp32 (N,F)
    const float* adj  = (const float*)d_in[1];   // fp32 (F,F)
    const float* W    = (const float*)d_in[2];   // fp32 (L,F,F)
    const float* bias = (const float*)d_in[3];   // fp32 (L,F)
    float* out = (float*)d_out;                  // fp32 (N,F)

    const int L = in_sizes[2] / in_sizes[1];     // 5
    const int F = in_sizes[3] / L;               // 1024
    const int N = in_sizes[0] / F;               // 16384

    const size_t nf = (size_t)N * F;
    const size_t ff = (size_t)F * F;

    // ws: WT all layers (L*ff bf16, 10.5 MB) + h_bf16 mirror (nf bf16,
    // 33.6 MB) = 44 MB, under the >=71 MB proven in R5.
    u16* WT = (u16*)d_ws;
    u16* Hb = WT + (size_t)L * ff;

    init_h<<<(unsigned)((nf / 4 + 255) / 256), 256, 0, stream>>>(x, out, Hb, nf / 4);
    prep_weights<<<dim3(F / 64, F / 64, L), 256, 0, stream>>>(W, adj, WT, F);

    const int nTiles = (N / BM) * (F / BN);
    for (int l = 0; l < L; ++l) {
        gemm_bf16<<<nTiles, 256, 0, stream>>>(
            Hb, WT + (size_t)l * ff, bias + (size_t)l * F, out, N, F, F);
        ln_fused<<<N, 256, 0, stream>>>(out, Hb, F);
    }
}